// Round 11
// baseline (329.940 us; speedup 1.0000x reference)
//
#include <hip/hip_runtime.h>
#include <math.h>

#define NN 8192
#define NE 32768
#define CC 32
#define EB 64

typedef __attribute__((ext_vector_type(8))) short s16x8;
typedef __attribute__((ext_vector_type(4))) float f32x4;

__device__ __forceinline__ unsigned short f2bf(float f) {
  unsigned u = __float_as_uint(f);
  u += 0x7FFFu + ((u >> 16) & 1u);
  return (unsigned short)(u >> 16);
}

// ---------------- edge preprocessing ----------------
__global__ void k_prep(const float* __restrict__ rel, const float* __restrict__ ef,
                       float* __restrict__ es, float* __restrict__ rhat) {
  int e = blockIdx.x * blockDim.x + threadIdx.x;
  if (e >= NE) return;
  float x = rel[e*3+0], y = rel[e*3+1], z = rel[e*3+2];
  float rn = sqrtf(x*x + y*y + z*z);
  float inv = 1.0f / (rn + 1e-12f);
  rhat[e*3+0] = x*inv; rhat[e*3+1] = y*inv; rhat[e*3+2] = z*inv;
  es[e*5+0] = rn;
  es[e*5+1] = ef[e*4+0];
  es[e*5+2] = ef[e*4+1];
  es[e*5+3] = ef[e*4+2];
  es[e*5+4] = ef[e*4+3];
}

// ---------------- CSR build over dst ----------------
__global__ void k_count(const int* __restrict__ dst, int* __restrict__ cnt) {
  int e = blockIdx.x * blockDim.x + threadIdx.x;
  if (e < NE) atomicAdd(&cnt[dst[e]], 1);
}

__global__ __launch_bounds__(1024) void k_scan(const int* __restrict__ cnt,
                                               int* __restrict__ offs, int* __restrict__ cursor) {
  __shared__ int part[1024];
  int t = threadIdx.x;
  int base = t * 8;
  int loc[8];
  int s = 0;
  #pragma unroll
  for (int j = 0; j < 8; ++j) { loc[j] = s; s += cnt[base + j]; }
  part[t] = s;
  __syncthreads();
  for (int off = 1; off < 1024; off <<= 1) {
    int v = (t >= off) ? part[t - off] : 0;
    __syncthreads();
    part[t] += v;
    __syncthreads();
  }
  int pre = (t == 0) ? 0 : part[t - 1];
  #pragma unroll
  for (int j = 0; j < 8; ++j) {
    int o = pre + loc[j];
    offs[base + j] = o;
    cursor[base + j] = o;
  }
  if (t == 1023) offs[NN] = part[1023];
}

__global__ void k_fill(const int* __restrict__ dst, int* __restrict__ cursor,
                       int* __restrict__ eidx) {
  int e = blockIdx.x * blockDim.x + threadIdx.x;
  if (e >= NE) return;
  int pos = atomicAdd(&cursor[dst[e]], 1);
  eidx[pos] = e;
}

// ---------------- radial hidden -> bf16 ----------------
__global__ void k_radial(const float* __restrict__ es, const float* __restrict__ W1,
                         const float* __restrict__ b1, const float* __restrict__ g,
                         const float* __restrict__ be, unsigned short* __restrict__ h) {
  int t = blockIdx.x * blockDim.x + threadIdx.x;
  int e = t >> 6, m = t & 63;
  if (e >= NE) return;
  const float* ep = es + (size_t)e*5;
  float v = b1[m];
  v = fmaf(ep[0], W1[0*64+m], v);
  v = fmaf(ep[1], W1[1*64+m], v);
  v = fmaf(ep[2], W1[2*64+m], v);
  v = fmaf(ep[3], W1[3*64+m], v);
  v = fmaf(ep[4], W1[4*64+m], v);
  float s = v;
  #pragma unroll
  for (int off = 32; off; off >>= 1) s += __shfl_xor(s, off);
  float mu = s * (1.0f/64.0f);
  float d = v - mu;
  float s2 = d*d;
  #pragma unroll
  for (int off = 32; off; off >>= 1) s2 += __shfl_xor(s2, off);
  float hv = d * rsqrtf(s2*(1.0f/64.0f) + 1e-5f) * g[m] + be[m];
  h[(size_t)e*64+m] = f2bf(fmaxf(hv, 0.0f));
}

// ---------------- W2 -> bf16, A-fragment order (M = col-in-group) ----------------
__global__ void k_w2cvt(const float* __restrict__ W2, unsigned short* __restrict__ dstp, int N) {
  int idx = blockIdx.x * blockDim.x + threadIdx.x;
  int total = (N >> 5) * 4 * 64;
  if (idx >= total) return;
  int l = idx & 63;
  int fr = idx >> 6;
  int kh = fr & 1;
  int mt = (fr >> 1) & 1;
  int g  = fr >> 2;
  int kb  = kh*32 + (l >> 4)*8;
  int col = g*32 + mt*16 + (l & 15);
  s16x8 v;
  #pragma unroll
  for (int j = 0; j < 8; ++j) v[j] = (short)f2bf(W2[(size_t)(kb + j)*N + col]);
  *reinterpret_cast<s16x8*>(dstp + (size_t)idx*8) = v;
}

#define MFMA_PAIR(gexpr)                                                  \
  const s16x8* ap = w2v + ((size_t)(gexpr)*4*64 + lane);                  \
  s16x8 a00 = ap[0], a01 = ap[64], a10 = ap[128], a11 = ap[192];          \
  f32x4 D0 = {0.f,0.f,0.f,0.f}, D1 = {0.f,0.f,0.f,0.f};                   \
  D0 = __builtin_amdgcn_mfma_f32_16x16x32_bf16(a00, bh0, D0, 0,0,0);      \
  D0 = __builtin_amdgcn_mfma_f32_16x16x32_bf16(a01, bh1, D0, 0,0,0);      \
  D1 = __builtin_amdgcn_mfma_f32_16x16x32_bf16(a10, bh0, D1, 0,0,0);      \
  D1 = __builtin_amdgcn_mfma_f32_16x16x32_bf16(a11, bh1, D1, 0,0,0);

// ---------------- fused conv: transposed MFMA, register accumulators, loop = loads+MFMA+FMA only ----
// m layout per edge (64 floats): [0..15]=m0, [16+o*3+a]=m1[o][a] (writer combines q01*rhat)
// 512 thr = 8 waves: et=wv&3 (edge-tile of 16), gp=wv>>2 (group parity). EB=64 edges/block.
__global__ __launch_bounds__(512) void k_conv_mfma(
    const unsigned short* __restrict__ hbf, const unsigned short* __restrict__ w2s,
    const float* __restrict__ f0, const float* __restrict__ f1,
    const float* __restrict__ rhat, const float* __restrict__ scale,
    const int* __restrict__ src, float* __restrict__ m_out)
{
  __shared__ float rhs[EB][4];
  __shared__ float scs[EB];
  __shared__ float macc[EB][81];
  int tid = threadIdx.x;
  int e0 = blockIdx.x * EB;

  for (int idx = tid; idx < EB; idx += 512) {
    rhs[idx][0] = rhat[(e0+idx)*3+0];
    rhs[idx][1] = rhat[(e0+idx)*3+1];
    rhs[idx][2] = rhat[(e0+idx)*3+2];
    scs[idx]    = scale[e0+idx];
  }

  int lane = tid & 63, wv = tid >> 6;
  int cl = lane & 15;
  int rb = ((lane >> 4) & 3) * 4;
  int ko = (lane >> 4) * 8;
  int et = wv & 3, gp = wv >> 2;
  int e  = et*16 + cl;

  const unsigned short* hb = hbf + (size_t)e0*64;
  s16x8 bh0 = *reinterpret_cast<const s16x8*>(hb + (size_t)e*64 + ko);
  s16x8 bh1 = *reinterpret_cast<const s16x8*>(hb + (size_t)e*64 + 32 + ko);
  const s16x8* w2v = reinterpret_cast<const s16x8*>(w2s);

  // hoist F-values straight from global (one time)
  int sn = src[e0+e];
  float rx = rhat[(e0+e)*3+0], ry = rhat[(e0+e)*3+1], rz = rhat[(e0+e)*3+2];
  float F0[8], T1[8], F1r[24];
  #pragma unroll
  for (int r = 0; r < 4; ++r) {
    int cA = rb + r, cB = 16 + rb + r;
    F0[r]   = f0[(size_t)sn*32 + cA];
    F0[4+r] = f0[(size_t)sn*32 + cB];
    #pragma unroll
    for (int a = 0; a < 3; ++a) {
      F1r[r*3+a]    = f1[(size_t)sn*96 + cA*3 + a];
      F1r[12+r*3+a] = f1[(size_t)sn*96 + cB*3 + a];
    }
  }
  #pragma unroll
  for (int r = 0; r < 4; ++r) {
    T1[r]   = rx*F1r[r*3+0]    + ry*F1r[r*3+1]    + rz*F1r[r*3+2];
    T1[4+r] = rx*F1r[12+r*3+0] + ry*F1r[12+r*3+1] + rz*F1r[12+r*3+2];
  }

  const float inv_s3 = 0.57735026919f;
  const float inv_s2 = 0.70710678118f;
  const float c15    = 1.22474487139f;

  float am0[8], aq[8], am1v[24];
  #pragma unroll
  for (int i = 0; i < 8; ++i) { am0[i] = 0.f; aq[i] = 0.f; }
  #pragma unroll
  for (int i = 0; i < 24; ++i) am1v[i] = 0.f;

  #pragma unroll
  for (int i = 0; i < 8; ++i) {         // R00: g = 2i+gp, with f0
    MFMA_PAIR(2*i + gp)
    #pragma unroll
    for (int r = 0; r < 4; ++r) {
      am0[i] = fmaf(D0[r], F0[r],   am0[i]);
      am0[i] = fmaf(D1[r], F0[4+r], am0[i]);
    }
  }
  #pragma unroll
  for (int i = 0; i < 8; ++i) {         // R01 -> q01: g = 16+2i+gp, with f0
    MFMA_PAIR(16 + 2*i + gp)
    #pragma unroll
    for (int r = 0; r < 4; ++r) {
      aq[i] = fmaf(D0[r], F0[r],   aq[i]);
      aq[i] = fmaf(D1[r], F0[4+r], aq[i]);
    }
  }
  #pragma unroll
  for (int i = 0; i < 8; ++i) {         // R10: g = 32+2i+gp, with t1
    MFMA_PAIR(32 + 2*i + gp)
    #pragma unroll
    for (int r = 0; r < 4; ++r) {
      am0[i] = fmaf(D0[r], T1[r],   am0[i]);
      am0[i] = fmaf(D1[r], T1[4+r], am0[i]);
    }
  }
  #pragma unroll
  for (int i = 0; i < 8; ++i) {         // R11 j3=0 (Q0 = I/sqrt3): g = 48+2i+gp
    MFMA_PAIR(48 + 2*i + gp)
    float v0=0.f, v1=0.f, v2=0.f;
    #pragma unroll
    for (int r = 0; r < 4; ++r) {
      v0 = fmaf(D0[r], F1r[r*3+0], v0); v0 = fmaf(D1[r], F1r[12+r*3+0], v0);
      v1 = fmaf(D0[r], F1r[r*3+1], v1); v1 = fmaf(D1[r], F1r[12+r*3+1], v1);
      v2 = fmaf(D0[r], F1r[r*3+2], v2); v2 = fmaf(D1[r], F1r[12+r*3+2], v2);
    }
    am1v[i*3+0] += v0*inv_s3;
    am1v[i*3+1] += v1*inv_s3;
    am1v[i*3+2] += v2*inv_s3;
  }
  #pragma unroll
  for (int i = 0; i < 8; ++i) {         // R11 j3=1 (Q1 = eps.rhat/sqrt2): g = 64+2i+gp
    MFMA_PAIR(64 + 2*i + gp)
    float v0=0.f, v1=0.f, v2=0.f;
    #pragma unroll
    for (int r = 0; r < 4; ++r) {
      v0 = fmaf(D0[r], F1r[r*3+0], v0); v0 = fmaf(D1[r], F1r[12+r*3+0], v0);
      v1 = fmaf(D0[r], F1r[r*3+1], v1); v1 = fmaf(D1[r], F1r[12+r*3+1], v1);
      v2 = fmaf(D0[r], F1r[r*3+2], v2); v2 = fmaf(D1[r], F1r[12+r*3+2], v2);
    }
    am1v[i*3+0] += (rz*v1 - ry*v2)*inv_s2;
    am1v[i*3+1] += (rx*v2 - rz*v0)*inv_s2;
    am1v[i*3+2] += (ry*v0 - rx*v1)*inv_s2;
  }
  #pragma unroll
  for (int i = 0; i < 8; ++i) {         // R11 j3=2 (Q2): g = 80+2i+gp
    MFMA_PAIR(80 + 2*i + gp)
    float v0=0.f, v1=0.f, v2=0.f, w=0.f;
    #pragma unroll
    for (int r = 0; r < 4; ++r) {
      v0 = fmaf(D0[r], F1r[r*3+0], v0); v0 = fmaf(D1[r], F1r[12+r*3+0], v0);
      v1 = fmaf(D0[r], F1r[r*3+1], v1); v1 = fmaf(D1[r], F1r[12+r*3+1], v1);
      v2 = fmaf(D0[r], F1r[r*3+2], v2); v2 = fmaf(D1[r], F1r[12+r*3+2], v2);
      w  = fmaf(D0[r], T1[r], w);       w  = fmaf(D1[r], T1[4+r], w);
    }
    am1v[i*3+0] += c15*(rx*w - v0*(1.0f/3.0f));
    am1v[i*3+1] += c15*(ry*w - v1*(1.0f/3.0f));
    am1v[i*3+2] += c15*(rz*w - v2*(1.0f/3.0f));
  }

  // one-time cross-quad reduction + store (each macc slot written exactly once)
  #pragma unroll
  for (int i = 0; i < 8; ++i) {
    am0[i] += __shfl_xor(am0[i], 16); am0[i] += __shfl_xor(am0[i], 32);
    aq[i]  += __shfl_xor(aq[i],  16); aq[i]  += __shfl_xor(aq[i],  32);
  }
  #pragma unroll
  for (int i = 0; i < 24; ++i) {
    am1v[i] += __shfl_xor(am1v[i], 16); am1v[i] += __shfl_xor(am1v[i], 32);
  }
  if (lane < 16) {
    #pragma unroll
    for (int i = 0; i < 8; ++i) {
      macc[e][2*i + gp]      = am0[i];
      macc[e][16 + 2*i + gp] = aq[i];
      #pragma unroll
      for (int a = 0; a < 3; ++a)
        macc[e][32 + (2*i + gp)*3 + a] = am1v[i*3 + a];
    }
  }
  __syncthreads();
  for (int idx = tid; idx < EB*64; idx += 512) {
    int e2 = idx >> 6, t2 = idx & 63;
    float sc = scs[e2];
    float val;
    if (t2 < 16) {
      val = macc[e2][t2] * sc;
    } else {
      int o = (t2-16)/3, a2 = (t2-16)%3;
      val = (macc[e2][32 + (t2-16)] + macc[e2][16+o]*rhs[e2][a2]) * sc;
    }
    m_out[(size_t)(e0+e2)*64 + t2] = val;
  }
}

// ---------------- queries ----------------
__global__ void k_query(const float* __restrict__ f0, const float* __restrict__ f1,
                        const float* __restrict__ Wq0, const float* __restrict__ Wq1,
                        float* __restrict__ q) {
  int n = blockIdx.x * blockDim.x + threadIdx.x;
  if (n >= NN) return;
  float q0[8]  = {0,0,0,0,0,0,0,0};
  float q1x[8] = {0,0,0,0,0,0,0,0};
  float q1y[8] = {0,0,0,0,0,0,0,0};
  float q1z[8] = {0,0,0,0,0,0,0,0};
  for (int c = 0; c < 32; ++c) {
    float fv = f0[(size_t)n*32+c];
    float fx = f1[(size_t)n*96+c*3+0];
    float fy = f1[(size_t)n*96+c*3+1];
    float fz = f1[(size_t)n*96+c*3+2];
    #pragma unroll
    for (int k = 0; k < 8; ++k) {
      float w0 = Wq0[c*8+k], w1 = Wq1[c*8+k];
      q0[k]  = fmaf(fv, w0, q0[k]);
      q1x[k] = fmaf(fx, w1, q1x[k]);
      q1y[k] = fmaf(fy, w1, q1y[k]);
      q1z[k] = fmaf(fz, w1, q1z[k]);
    }
  }
  #pragma unroll
  for (int k = 0; k < 8; ++k) {
    q[(size_t)n*32+k]         = q0[k];
    q[(size_t)n*32+8+k*3+0]   = q1x[k];
    q[(size_t)n*32+8+k*3+1]   = q1y[k];
    q[(size_t)n*32+8+k*3+2]   = q1z[k];
  }
}

// ---------------- attention: CSR gather + online softmax, thread per (node, head) ----------------
__global__ void k_attn(const float* __restrict__ m, const float* __restrict__ q,
                       const int* __restrict__ offs, const int* __restrict__ eidx,
                       float* __restrict__ o0, float* __restrict__ o1) {
  int idx = blockIdx.x * blockDim.x + threadIdx.x;
  int n = idx >> 3, h = idx & 7;
  if (n >= NN) return;
  const float* qd = q + (size_t)n*32 + 4*h;
  float q0 = qd[0], q1 = qd[1], q2 = qd[2], q3 = qd[3];
  int kb = (h < 2) ? 4*h : 8 + 4*h;
  int b0 = offs[n], b1 = offs[n+1];
  float M = -3.4e38f, D = 0.f, A0 = 0.f, Ax = 0.f, Ay = 0.f, Az = 0.f;
  for (int j = b0; j < b1; ++j) {
    int e = eidx[j];
    const float* me = m + (size_t)e*64;
    float4 kv = *reinterpret_cast<const float4*>(me + kb);
    float l = 0.5f * (kv.x*q0 + kv.y*q1 + kv.z*q2 + kv.w*q3);
    float v0 = me[8+h];
    float vx = me[40+3*h], vy = me[41+3*h], vz = me[42+3*h];
    if (l > M) {
      float sc = __expf(M - l);
      D *= sc; A0 *= sc; Ax *= sc; Ay *= sc; Az *= sc;
      M = l;
    }
    float z = __expf(l - M);
    D += z;
    A0 = fmaf(z, v0, A0);
    Ax = fmaf(z, vx, Ax);
    Ay = fmaf(z, vy, Ay);
    Az = fmaf(z, vz, Az);
  }
  float inv = 1.0f / (D + 1e-9f);
  o0[(size_t)n*8+h] = A0*inv;
  o1[(size_t)n*24+3*h+0] = Ax*inv;
  o1[(size_t)n*24+3*h+1] = Ay*inv;
  o1[(size_t)n*24+3*h+2] = Az*inv;
}

// ---------------- projection + NormSE3 ----------------
__global__ void k_update(const float* __restrict__ o0, const float* __restrict__ o1,
                         const float* __restrict__ f0c, const float* __restrict__ f1c,
                         const float* __restrict__ Wp0, const float* __restrict__ Wp1,
                         const float* __restrict__ ng0v, const float* __restrict__ nb0v,
                         const float* __restrict__ ng1v, const float* __restrict__ nb1v,
                         float* __restrict__ f0o, float* __restrict__ f1o) {
  int t = blockIdx.x * blockDim.x + threadIdx.x;
  int n = t >> 5, o = t & 31;
  if (n >= NN) return;
  float a0 = 0.0f, ax = 0.0f, ay = 0.0f, az = 0.0f;
  for (int c = 0; c < 8; ++c) {
    float w0 = Wp0[c*32+o], w1 = Wp1[c*32+o];
    a0 = fmaf(o0[(size_t)n*8+c], w0, a0);
    ax = fmaf(o1[(size_t)n*24+c*3+0], w1, ax);
    ay = fmaf(o1[(size_t)n*24+c*3+1], w1, ay);
    az = fmaf(o1[(size_t)n*24+c*3+2], w1, az);
  }
  for (int c = 0; c < 32; ++c) {
    float w0 = Wp0[(8+c)*32+o], w1 = Wp1[(8+c)*32+o];
    a0 = fmaf(f0c[(size_t)n*32+c], w0, a0);
    ax = fmaf(f1c[(size_t)n*96+c*3+0], w1, ax);
    ay = fmaf(f1c[(size_t)n*96+c*3+1], w1, ay);
    az = fmaf(f1c[(size_t)n*96+c*3+2], w1, az);
  }
  float nn0 = sqrtf(a0*a0 + 1e-12f);
  float nn1 = sqrtf(ax*ax + ay*ay + az*az + 1e-12f);
  float s0 = nn0, s1 = nn1;
  #pragma unroll
  for (int off = 16; off; off >>= 1) { s0 += __shfl_xor(s0, off, 32); s1 += __shfl_xor(s1, off, 32); }
  float mu0 = s0*(1.0f/32.0f), mu1 = s1*(1.0f/32.0f);
  float d0 = nn0 - mu0, d1 = nn1 - mu1;
  float v0 = d0*d0, v1 = d1*d1;
  #pragma unroll
  for (int off = 16; off; off >>= 1) { v0 += __shfl_xor(v0, off, 32); v1 += __shfl_xor(v1, off, 32); }
  float g0 = fmaxf(d0*rsqrtf(v0*(1.0f/32.0f)+1e-5f)*ng0v[o] + nb0v[o], 0.0f) / nn0;
  float g1 = fmaxf(d1*rsqrtf(v1*(1.0f/32.0f)+1e-5f)*ng1v[o] + nb1v[o], 0.0f) / nn1;
  f0o[(size_t)n*32+o] = a0*g0;
  f1o[(size_t)n*96+o*3+0] = ax*g1;
  f1o[(size_t)n*96+o*3+1] = ay*g1;
  f1o[(size_t)n*96+o*3+2] = az*g1;
}

// ---------------- final conv: transposed MFMA, register accumulators -> scatter ----------------
__global__ __launch_bounds__(512) void k_fconv_mfma(
    const unsigned short* __restrict__ hbf, const unsigned short* __restrict__ w2s,
    const float* __restrict__ f0, const float* __restrict__ f1,
    const float* __restrict__ rhat, const float* __restrict__ scale,
    const int* __restrict__ src, const int* __restrict__ dst, float* __restrict__ out)
{
  __shared__ float macc[EB][17];
  __shared__ float scs[EB];
  int tid = threadIdx.x;
  int e0 = blockIdx.x * EB;

  for (int idx = tid; idx < EB; idx += 512) scs[idx] = scale[e0+idx];

  int lane = tid & 63, wv = tid >> 6;
  int cl = lane & 15;
  int rb = ((lane >> 4) & 3) * 4;
  int ko = (lane >> 4) * 8;
  int et = wv & 3, gp = wv >> 2;
  int e  = et*16 + cl;

  const unsigned short* hb = hbf + (size_t)e0*64;
  s16x8 bh0 = *reinterpret_cast<const s16x8*>(hb + (size_t)e*64 + ko);
  s16x8 bh1 = *reinterpret_cast<const s16x8*>(hb + (size_t)e*64 + 32 + ko);
  const s16x8* w2v = reinterpret_cast<const s16x8*>(w2s);

  int sn = src[e0+e];
  float rx = rhat[(e0+e)*3+0], ry = rhat[(e0+e)*3+1], rz = rhat[(e0+e)*3+2];
  float F0[8], T1[8];
  #pragma unroll
  for (int r = 0; r < 4; ++r) {
    int cA = rb + r, cB = 16 + rb + r;
    F0[r]   = f0[(size_t)sn*32 + cA];
    F0[4+r] = f0[(size_t)sn*32 + cB];
    float ax0 = f1[(size_t)sn*96 + cA*3 + 0];
    float ax1 = f1[(size_t)sn*96 + cA*3 + 1];
    float ax2 = f1[(size_t)sn*96 + cA*3 + 2];
    float bx0 = f1[(size_t)sn*96 + cB*3 + 0];
    float bx1 = f1[(size_t)sn*96 + cB*3 + 1];
    float bx2 = f1[(size_t)sn*96 + cB*3 + 2];
    T1[r]   = rx*ax0 + ry*ax1 + rz*ax2;
    T1[4+r] = rx*bx0 + ry*bx1 + rz*bx2;
  }

  float am[8];
  #pragma unroll
  for (int i = 0; i < 8; ++i) am[i] = 0.f;

  #pragma unroll
  for (int i = 0; i < 8; ++i) {          // Rf00: g = 2i+gp
    MFMA_PAIR(2*i + gp)
    #pragma unroll
    for (int r = 0; r < 4; ++r) {
      am[i] = fmaf(D0[r], F0[r],   am[i]);
      am[i] = fmaf(D1[r], F0[4+r], am[i]);
    }
  }
  #pragma unroll
  for (int i = 0; i < 8; ++i) {          // Rf10: g = 16+2i+gp
    MFMA_PAIR(16 + 2*i + gp)
    #pragma unroll
    for (int r = 0; r < 4; ++r) {
      am[i] = fmaf(D0[r], T1[r],   am[i]);
      am[i] = fmaf(D1[r], T1[4+r], am[i]);
    }
  }

  #pragma unroll
  for (int i = 0; i < 8; ++i) {
    am[i] += __shfl_xor(am[i], 16); am[i] += __shfl_xor(am[i], 32);
  }
  if (lane < 16) {
    #pragma unroll
    for (int i = 0; i < 8; ++i) macc[e][2*i + gp] = am[i];
  }
  __syncthreads();
  for (int idx = tid; idx < EB*16; idx += 512) {
    int e2 = idx >> 4, o = idx & 15;
    atomicAdd(&out[(size_t)dst[e0+e2]*16 + o], macc[e2][o]*scs[e2]);
  }
}

extern "C" void kernel_launch(void* const* d_in, const int* in_sizes, int n_in,
                              void* d_out, int out_size, void* d_ws, size_t ws_size,
                              hipStream_t stream) {
  (void)in_sizes; (void)n_in; (void)ws_size;
  const float* nf0  = (const float*)d_in[0];
  const float* nf1  = (const float*)d_in[1];
  const float* ef0  = (const float*)d_in[2];
  const float* rel  = (const float*)d_in[3];
  const float* scale= (const float*)d_in[4];
  const int*   src  = (const int*)d_in[5];
  const int*   dst  = (const int*)d_in[6];
  const float* rW1  = (const float*)d_in[7];
  const float* rb1  = (const float*)d_in[8];
  const float* rg   = (const float*)d_in[9];
  const float* rbe  = (const float*)d_in[10];
  const float* rW2  = (const float*)d_in[11];
  const float* Wq0  = (const float*)d_in[12];
  const float* Wq1  = (const float*)d_in[13];
  const float* Wp0  = (const float*)d_in[14];
  const float* Wp1  = (const float*)d_in[15];
  const float* ng0  = (const float*)d_in[16];
  const float* nb0  = (const float*)d_in[17];
  const float* ng1  = (const float*)d_in[18];
  const float* nb1  = (const float*)d_in[19];
  const float* fW1  = (const float*)d_in[20];
  const float* fb1  = (const float*)d_in[21];
  const float* fg   = (const float*)d_in[22];
  const float* fbe  = (const float*)d_in[23];
  const float* fW2  = (const float*)d_in[24];

  float* ws = (float*)d_ws;
  size_t off = 0;
  float* es    = ws + off; off += (size_t)NE*5;
  float* rhat  = ws + off; off += (size_t)NE*3;
  float* m     = ws + off; off += (size_t)NE*64;
  float* q     = ws + off; off += (size_t)NN*32;
  float* o0    = ws + off; off += (size_t)NN*8;
  float* o1    = ws + off; off += (size_t)NN*24;
  float* f0a   = ws + off; off += (size_t)NN*32;
  float* f1a   = ws + off; off += (size_t)NN*96;
  float* f0b   = ws + off; off += (size_t)NN*32;
  float* f1b   = ws + off; off += (size_t)NN*96;
  int* cnt     = (int*)(ws + off); off += NN;
  int* offs    = (int*)(ws + off); off += NN + 1;
  int* cursor  = (int*)(ws + off); off += NN;
  int* eidx    = (int*)(ws + off); off += NE;
  unsigned short* usbase = (unsigned short*)(ws + off);
  unsigned short* hbf  = usbase;                               // NE*64
  unsigned short* w2s0 = hbf  + (size_t)NE*64;                 // 96*4*64*8 = 196608
  unsigned short* w2s1 = w2s0 + 196608;
  unsigned short* w2sf = w2s1 + 196608;                        // 32*4*64*8 = 65536

  // CSR build over dst
  hipMemsetAsync(cnt, 0, NN*sizeof(int), stream);
  k_count<<<NE/256, 256, 0, stream>>>(dst, cnt);
  k_scan<<<1, 1024, 0, stream>>>(cnt, offs, cursor);
  k_fill<<<NE/256, 256, 0, stream>>>(dst, cursor, eidx);

  // weight pre-swizzle (bf16 A-fragment order)
  k_w2cvt<<<96, 256, 0, stream>>>(rW2,            w2s0, 3072);
  k_w2cvt<<<96, 256, 0, stream>>>(rW2 + 64*3072,  w2s1, 3072);
  k_w2cvt<<<32, 256, 0, stream>>>(fW2,            w2sf, 1024);

  k_prep<<<NE/256, 256, 0, stream>>>(rel, ef0, es, rhat);

  const float* f0c = nf0; const float* f1c = nf1;
  float* f0n = f0a; float* f1n = f1a;
  for (int l = 0; l < 2; ++l) {
    k_radial<<<NE*64/256, 256, 0, stream>>>(es, rW1 + l*320, rb1 + l*64, rg + l*64, rbe + l*64, hbf);
    k_conv_mfma<<<NE/EB, 512, 0, stream>>>(hbf, (l == 0) ? w2s0 : w2s1, f0c, f1c, rhat, scale, src, m);
    k_query<<<NN/256, 256, 0, stream>>>(f0c, f1c, Wq0 + l*256, Wq1 + l*256, q);
    k_attn<<<NN*8/256, 256, 0, stream>>>(m, q, offs, eidx, o0, o1);
    k_update<<<NN*32/256, 256, 0, stream>>>(o0, o1, f0c, f1c, Wp0 + l*1280, Wp1 + l*1280,
                                            ng0 + l*32, nb0 + l*32, ng1 + l*32, nb1 + l*32,
                                            f0n, f1n);
    f0c = f0n; f1c = f1n; f0n = f0b; f1n = f1b;
  }
  k_radial<<<NE*64/256, 256, 0, stream>>>(es, fW1, fb1, fg, fbe, hbf);
  hipMemsetAsync(d_out, 0, (size_t)out_size*sizeof(float), stream);
  k_fconv_mfma<<<NE/EB, 512, 0, stream>>>(hbf, w2sf, f0c, f1c, rhat, scale, src, dst, (float*)d_out);
}

// Round 12
// 292.229 us; speedup vs baseline: 1.1290x; 1.1290x over previous
//
#include <hip/hip_runtime.h>
#include <math.h>

#define NN 8192
#define NE 32768
#define CC 32
#define EB 64

typedef __attribute__((ext_vector_type(8))) short s16x8;
typedef __attribute__((ext_vector_type(4))) float f32x4;

__device__ __forceinline__ unsigned short f2bf(float f) {
  unsigned u = __float_as_uint(f);
  u += 0x7FFFu + ((u >> 16) & 1u);
  return (unsigned short)(u >> 16);
}

__device__ __forceinline__ void mfma_pair(const s16x8* __restrict__ w2v, int g, int lane,
                                          s16x8 bh0, s16x8 bh1, f32x4& D0, f32x4& D1) {
  const s16x8* ap = w2v + ((size_t)g*4*64 + lane);
  s16x8 a00 = ap[0], a01 = ap[64], a10 = ap[128], a11 = ap[192];
  f32x4 z = {0.f,0.f,0.f,0.f};
  D0 = __builtin_amdgcn_mfma_f32_16x16x32_bf16(a00, bh0, z, 0,0,0);
  D0 = __builtin_amdgcn_mfma_f32_16x16x32_bf16(a01, bh1, D0, 0,0,0);
  D1 = __builtin_amdgcn_mfma_f32_16x16x32_bf16(a10, bh0, z, 0,0,0);
  D1 = __builtin_amdgcn_mfma_f32_16x16x32_bf16(a11, bh1, D1, 0,0,0);
}

// ---------------- edge preprocessing ----------------
__global__ void k_prep(const float* __restrict__ rel, const float* __restrict__ ef,
                       float* __restrict__ es, float* __restrict__ rhat) {
  int e = blockIdx.x * blockDim.x + threadIdx.x;
  if (e >= NE) return;
  float x = rel[e*3+0], y = rel[e*3+1], z = rel[e*3+2];
  float rn = sqrtf(x*x + y*y + z*z);
  float inv = 1.0f / (rn + 1e-12f);
  rhat[e*3+0] = x*inv; rhat[e*3+1] = y*inv; rhat[e*3+2] = z*inv;
  es[e*5+0] = rn;
  es[e*5+1] = ef[e*4+0];
  es[e*5+2] = ef[e*4+1];
  es[e*5+3] = ef[e*4+2];
  es[e*5+4] = ef[e*4+3];
}

// ---------------- CSR build over dst ----------------
__global__ void k_count(const int* __restrict__ dst, int* __restrict__ cnt) {
  int e = blockIdx.x * blockDim.x + threadIdx.x;
  if (e < NE) atomicAdd(&cnt[dst[e]], 1);
}

__global__ __launch_bounds__(1024) void k_scan(const int* __restrict__ cnt,
                                               int* __restrict__ offs, int* __restrict__ cursor) {
  __shared__ int part[1024];
  int t = threadIdx.x;
  int base = t * 8;
  int loc[8];
  int s = 0;
  #pragma unroll
  for (int j = 0; j < 8; ++j) { loc[j] = s; s += cnt[base + j]; }
  part[t] = s;
  __syncthreads();
  for (int off = 1; off < 1024; off <<= 1) {
    int v = (t >= off) ? part[t - off] : 0;
    __syncthreads();
    part[t] += v;
    __syncthreads();
  }
  int pre = (t == 0) ? 0 : part[t - 1];
  #pragma unroll
  for (int j = 0; j < 8; ++j) {
    int o = pre + loc[j];
    offs[base + j] = o;
    cursor[base + j] = o;
  }
  if (t == 1023) offs[NN] = part[1023];
}

__global__ void k_fill(const int* __restrict__ dst, int* __restrict__ cursor,
                       int* __restrict__ eidx) {
  int e = blockIdx.x * blockDim.x + threadIdx.x;
  if (e >= NE) return;
  int pos = atomicAdd(&cursor[dst[e]], 1);
  eidx[pos] = e;
}

// ---------------- radial hidden -> bf16 ----------------
__global__ void k_radial(const float* __restrict__ es, const float* __restrict__ W1,
                         const float* __restrict__ b1, const float* __restrict__ g,
                         const float* __restrict__ be, unsigned short* __restrict__ h) {
  int t = blockIdx.x * blockDim.x + threadIdx.x;
  int e = t >> 6, m = t & 63;
  if (e >= NE) return;
  const float* ep = es + (size_t)e*5;
  float v = b1[m];
  v = fmaf(ep[0], W1[0*64+m], v);
  v = fmaf(ep[1], W1[1*64+m], v);
  v = fmaf(ep[2], W1[2*64+m], v);
  v = fmaf(ep[3], W1[3*64+m], v);
  v = fmaf(ep[4], W1[4*64+m], v);
  float s = v;
  #pragma unroll
  for (int off = 32; off; off >>= 1) s += __shfl_xor(s, off);
  float mu = s * (1.0f/64.0f);
  float d = v - mu;
  float s2 = d*d;
  #pragma unroll
  for (int off = 32; off; off >>= 1) s2 += __shfl_xor(s2, off);
  float hv = d * rsqrtf(s2*(1.0f/64.0f) + 1e-5f) * g[m] + be[m];
  h[(size_t)e*64+m] = f2bf(fmaxf(hv, 0.0f));
}

// ---------------- W2 -> bf16, A-fragment order (M = col-in-group) ----------------
__global__ void k_w2cvt(const float* __restrict__ W2, unsigned short* __restrict__ dstp, int N) {
  int idx = blockIdx.x * blockDim.x + threadIdx.x;
  int total = (N >> 5) * 4 * 64;
  if (idx >= total) return;
  int l = idx & 63;
  int fr = idx >> 6;
  int kh = fr & 1;
  int mt = (fr >> 1) & 1;
  int g  = fr >> 2;
  int kb  = kh*32 + (l >> 4)*8;
  int col = g*32 + mt*16 + (l & 15);
  s16x8 v;
  #pragma unroll
  for (int j = 0; j < 8; ++j) v[j] = (short)f2bf(W2[(size_t)(kb + j)*N + col]);
  *reinterpret_cast<s16x8*>(dstp + (size_t)idx*8) = v;
}

// ---------------- fused conv: transposed MFMA, one fused phase-loop (unroll 1) ----------------
// m layout per edge (64 floats): [0..15]=m0, [16+o*3+a]=m1[o][a] (writer combines q01*rhat)
// 512 thr = 8 waves: et=wv&3 (edge-tile of 16), gp=wv>>2 (group parity). EB=64 edges/block.
__global__ __launch_bounds__(512) void k_conv_mfma(
    const unsigned short* __restrict__ hbf, const unsigned short* __restrict__ w2s,
    const float* __restrict__ f0, const float* __restrict__ f1,
    const float* __restrict__ rhat, const float* __restrict__ scale,
    const int* __restrict__ src, float* __restrict__ m_out)
{
  __shared__ float rhs[EB][4];
  __shared__ float scs[EB];
  __shared__ float macc[EB][81];
  int tid = threadIdx.x;
  int e0 = blockIdx.x * EB;

  for (int idx = tid; idx < EB; idx += 512) {
    rhs[idx][0] = rhat[(e0+idx)*3+0];
    rhs[idx][1] = rhat[(e0+idx)*3+1];
    rhs[idx][2] = rhat[(e0+idx)*3+2];
    scs[idx]    = scale[e0+idx];
  }

  int lane = tid & 63, wv = tid >> 6;
  int cl = lane & 15;
  int rb = ((lane >> 4) & 3) * 4;
  int ko = (lane >> 4) * 8;
  int et = wv & 3, gp = wv >> 2;
  int e  = et*16 + cl;

  const unsigned short* hb = hbf + (size_t)e0*64;
  s16x8 bh0 = *reinterpret_cast<const s16x8*>(hb + (size_t)e*64 + ko);
  s16x8 bh1 = *reinterpret_cast<const s16x8*>(hb + (size_t)e*64 + 32 + ko);
  const s16x8* w2v = reinterpret_cast<const s16x8*>(w2s);

  // hoist F-values straight from global (one time)
  int sn = src[e0+e];
  float rx = rhat[(e0+e)*3+0], ry = rhat[(e0+e)*3+1], rz = rhat[(e0+e)*3+2];
  float F0[8], T1[8], F1r[24];
  #pragma unroll
  for (int r = 0; r < 4; ++r) {
    int cA = rb + r, cB = 16 + rb + r;
    F0[r]   = f0[(size_t)sn*32 + cA];
    F0[4+r] = f0[(size_t)sn*32 + cB];
    #pragma unroll
    for (int a = 0; a < 3; ++a) {
      F1r[r*3+a]    = f1[(size_t)sn*96 + cA*3 + a];
      F1r[12+r*3+a] = f1[(size_t)sn*96 + cB*3 + a];
    }
  }
  #pragma unroll
  for (int r = 0; r < 4; ++r) {
    T1[r]   = rx*F1r[r*3+0]    + ry*F1r[r*3+1]    + rz*F1r[r*3+2];
    T1[4+r] = rx*F1r[12+r*3+0] + ry*F1r[12+r*3+1] + rz*F1r[12+r*3+2];
  }

  const float inv_s3 = 0.57735026919f;
  const float inv_s2 = 0.70710678118f;
  const float c15    = 1.22474487139f;

  // one fused loop: each iteration finishes output index g = 2i+gp completely.
  #pragma unroll 1
  for (int i = 0; i < 8; ++i) {
    int g = 2*i + gp;
    float m0v, qv, m1x, m1y, m1z;
    {
      f32x4 D0, D1;
      mfma_pair(w2v, g, lane, bh0, bh1, D0, D1);          // R00
      float p = 0.f;
      #pragma unroll
      for (int r = 0; r < 4; ++r) { p = fmaf(D0[r], F0[r], p); p = fmaf(D1[r], F0[4+r], p); }
      m0v = p;
    }
    {
      f32x4 D0, D1;
      mfma_pair(w2v, 16 + g, lane, bh0, bh1, D0, D1);     // R01 -> q01
      float p = 0.f;
      #pragma unroll
      for (int r = 0; r < 4; ++r) { p = fmaf(D0[r], F0[r], p); p = fmaf(D1[r], F0[4+r], p); }
      qv = p;
    }
    {
      f32x4 D0, D1;
      mfma_pair(w2v, 32 + g, lane, bh0, bh1, D0, D1);     // R10
      float p = 0.f;
      #pragma unroll
      for (int r = 0; r < 4; ++r) { p = fmaf(D0[r], T1[r], p); p = fmaf(D1[r], T1[4+r], p); }
      m0v += p;
    }
    {
      f32x4 D0, D1;
      mfma_pair(w2v, 48 + g, lane, bh0, bh1, D0, D1);     // R11 j3=0 (Q0 = I/sqrt3)
      float v0=0.f, v1=0.f, v2=0.f;
      #pragma unroll
      for (int r = 0; r < 4; ++r) {
        v0 = fmaf(D0[r], F1r[r*3+0], v0); v0 = fmaf(D1[r], F1r[12+r*3+0], v0);
        v1 = fmaf(D0[r], F1r[r*3+1], v1); v1 = fmaf(D1[r], F1r[12+r*3+1], v1);
        v2 = fmaf(D0[r], F1r[r*3+2], v2); v2 = fmaf(D1[r], F1r[12+r*3+2], v2);
      }
      m1x = v0*inv_s3; m1y = v1*inv_s3; m1z = v2*inv_s3;
    }
    {
      f32x4 D0, D1;
      mfma_pair(w2v, 64 + g, lane, bh0, bh1, D0, D1);     // R11 j3=1 (Q1 = eps.rhat/sqrt2)
      float v0=0.f, v1=0.f, v2=0.f;
      #pragma unroll
      for (int r = 0; r < 4; ++r) {
        v0 = fmaf(D0[r], F1r[r*3+0], v0); v0 = fmaf(D1[r], F1r[12+r*3+0], v0);
        v1 = fmaf(D0[r], F1r[r*3+1], v1); v1 = fmaf(D1[r], F1r[12+r*3+1], v1);
        v2 = fmaf(D0[r], F1r[r*3+2], v2); v2 = fmaf(D1[r], F1r[12+r*3+2], v2);
      }
      m1x += (rz*v1 - ry*v2)*inv_s2;
      m1y += (rx*v2 - rz*v0)*inv_s2;
      m1z += (ry*v0 - rx*v1)*inv_s2;
    }
    {
      f32x4 D0, D1;
      mfma_pair(w2v, 80 + g, lane, bh0, bh1, D0, D1);     // R11 j3=2 (Q2)
      float v0=0.f, v1=0.f, v2=0.f, w=0.f;
      #pragma unroll
      for (int r = 0; r < 4; ++r) {
        v0 = fmaf(D0[r], F1r[r*3+0], v0); v0 = fmaf(D1[r], F1r[12+r*3+0], v0);
        v1 = fmaf(D0[r], F1r[r*3+1], v1); v1 = fmaf(D1[r], F1r[12+r*3+1], v1);
        v2 = fmaf(D0[r], F1r[r*3+2], v2); v2 = fmaf(D1[r], F1r[12+r*3+2], v2);
        w  = fmaf(D0[r], T1[r], w);       w  = fmaf(D1[r], T1[4+r], w);
      }
      m1x += c15*(rx*w - v0*(1.0f/3.0f));
      m1y += c15*(ry*w - v1*(1.0f/3.0f));
      m1z += c15*(rz*w - v2*(1.0f/3.0f));
    }
    // quad-reduce the 5 finished scalars, store once
    m0v += __shfl_xor(m0v, 16); m0v += __shfl_xor(m0v, 32);
    qv  += __shfl_xor(qv,  16); qv  += __shfl_xor(qv,  32);
    m1x += __shfl_xor(m1x, 16); m1x += __shfl_xor(m1x, 32);
    m1y += __shfl_xor(m1y, 16); m1y += __shfl_xor(m1y, 32);
    m1z += __shfl_xor(m1z, 16); m1z += __shfl_xor(m1z, 32);
    if (lane < 16) {
      macc[e][g]          = m0v;
      macc[e][16 + g]     = qv;
      macc[e][32 + g*3+0] = m1x;
      macc[e][32 + g*3+1] = m1y;
      macc[e][32 + g*3+2] = m1z;
    }
  }
  __syncthreads();
  for (int idx = tid; idx < EB*64; idx += 512) {
    int e2 = idx >> 6, t2 = idx & 63;
    float sc = scs[e2];
    float val;
    if (t2 < 16) {
      val = macc[e2][t2] * sc;
    } else {
      int o = (t2-16)/3, a2 = (t2-16)%3;
      val = (macc[e2][32 + (t2-16)] + macc[e2][16+o]*rhs[e2][a2]) * sc;
    }
    m_out[(size_t)(e0+e2)*64 + t2] = val;
  }
}

// ---------------- queries ----------------
__global__ void k_query(const float* __restrict__ f0, const float* __restrict__ f1,
                        const float* __restrict__ Wq0, const float* __restrict__ Wq1,
                        float* __restrict__ q) {
  int n = blockIdx.x * blockDim.x + threadIdx.x;
  if (n >= NN) return;
  float q0[8]  = {0,0,0,0,0,0,0,0};
  float q1x[8] = {0,0,0,0,0,0,0,0};
  float q1y[8] = {0,0,0,0,0,0,0,0};
  float q1z[8] = {0,0,0,0,0,0,0,0};
  for (int c = 0; c < 32; ++c) {
    float fv = f0[(size_t)n*32+c];
    float fx = f1[(size_t)n*96+c*3+0];
    float fy = f1[(size_t)n*96+c*3+1];
    float fz = f1[(size_t)n*96+c*3+2];
    #pragma unroll
    for (int k = 0; k < 8; ++k) {
      float w0 = Wq0[c*8+k], w1 = Wq1[c*8+k];
      q0[k]  = fmaf(fv, w0, q0[k]);
      q1x[k] = fmaf(fx, w1, q1x[k]);
      q1y[k] = fmaf(fy, w1, q1y[k]);
      q1z[k] = fmaf(fz, w1, q1z[k]);
    }
  }
  #pragma unroll
  for (int k = 0; k < 8; ++k) {
    q[(size_t)n*32+k]         = q0[k];
    q[(size_t)n*32+8+k*3+0]   = q1x[k];
    q[(size_t)n*32+8+k*3+1]   = q1y[k];
    q[(size_t)n*32+8+k*3+2]   = q1z[k];
  }
}

// ---------------- attention: CSR gather + online softmax, thread per (node, head) ----------------
__global__ void k_attn(const float* __restrict__ m, const float* __restrict__ q,
                       const int* __restrict__ offs, const int* __restrict__ eidx,
                       float* __restrict__ o0, float* __restrict__ o1) {
  int idx = blockIdx.x * blockDim.x + threadIdx.x;
  int n = idx >> 3, h = idx & 7;
  if (n >= NN) return;
  const float* qd = q + (size_t)n*32 + 4*h;
  float q0 = qd[0], q1 = qd[1], q2 = qd[2], q3 = qd[3];
  int kb = (h < 2) ? 4*h : 8 + 4*h;
  int b0 = offs[n], b1 = offs[n+1];
  float M = -3.4e38f, D = 0.f, A0 = 0.f, Ax = 0.f, Ay = 0.f, Az = 0.f;
  for (int j = b0; j < b1; ++j) {
    int e = eidx[j];
    const float* me = m + (size_t)e*64;
    float4 kv = *reinterpret_cast<const float4*>(me + kb);
    float l = 0.5f * (kv.x*q0 + kv.y*q1 + kv.z*q2 + kv.w*q3);
    float v0 = me[8+h];
    float vx = me[40+3*h], vy = me[41+3*h], vz = me[42+3*h];
    if (l > M) {
      float sc = __expf(M - l);
      D *= sc; A0 *= sc; Ax *= sc; Ay *= sc; Az *= sc;
      M = l;
    }
    float z = __expf(l - M);
    D += z;
    A0 = fmaf(z, v0, A0);
    Ax = fmaf(z, vx, Ax);
    Ay = fmaf(z, vy, Ay);
    Az = fmaf(z, vz, Az);
  }
  float inv = 1.0f / (D + 1e-9f);
  o0[(size_t)n*8+h] = A0*inv;
  o1[(size_t)n*24+3*h+0] = Ax*inv;
  o1[(size_t)n*24+3*h+1] = Ay*inv;
  o1[(size_t)n*24+3*h+2] = Az*inv;
}

// ---------------- projection + NormSE3 ----------------
__global__ void k_update(const float* __restrict__ o0, const float* __restrict__ o1,
                         const float* __restrict__ f0c, const float* __restrict__ f1c,
                         const float* __restrict__ Wp0, const float* __restrict__ Wp1,
                         const float* __restrict__ ng0v, const float* __restrict__ nb0v,
                         const float* __restrict__ ng1v, const float* __restrict__ nb1v,
                         float* __restrict__ f0o, float* __restrict__ f1o) {
  int t = blockIdx.x * blockDim.x + threadIdx.x;
  int n = t >> 5, o = t & 31;
  if (n >= NN) return;
  float a0 = 0.0f, ax = 0.0f, ay = 0.0f, az = 0.0f;
  for (int c = 0; c < 8; ++c) {
    float w0 = Wp0[c*32+o], w1 = Wp1[c*32+o];
    a0 = fmaf(o0[(size_t)n*8+c], w0, a0);
    ax = fmaf(o1[(size_t)n*24+c*3+0], w1, ax);
    ay = fmaf(o1[(size_t)n*24+c*3+1], w1, ay);
    az = fmaf(o1[(size_t)n*24+c*3+2], w1, az);
  }
  for (int c = 0; c < 32; ++c) {
    float w0 = Wp0[(8+c)*32+o], w1 = Wp1[(8+c)*32+o];
    a0 = fmaf(f0c[(size_t)n*32+c], w0, a0);
    ax = fmaf(f1c[(size_t)n*96+c*3+0], w1, ax);
    ay = fmaf(f1c[(size_t)n*96+c*3+1], w1, ay);
    az = fmaf(f1c[(size_t)n*96+c*3+2], w1, az);
  }
  float nn0 = sqrtf(a0*a0 + 1e-12f);
  float nn1 = sqrtf(ax*ax + ay*ay + az*az + 1e-12f);
  float s0 = nn0, s1 = nn1;
  #pragma unroll
  for (int off = 16; off; off >>= 1) { s0 += __shfl_xor(s0, off, 32); s1 += __shfl_xor(s1, off, 32); }
  float mu0 = s0*(1.0f/32.0f), mu1 = s1*(1.0f/32.0f);
  float d0 = nn0 - mu0, d1 = nn1 - mu1;
  float v0 = d0*d0, v1 = d1*d1;
  #pragma unroll
  for (int off = 16; off; off >>= 1) { v0 += __shfl_xor(v0, off, 32); v1 += __shfl_xor(v1, off, 32); }
  float g0 = fmaxf(d0*rsqrtf(v0*(1.0f/32.0f)+1e-5f)*ng0v[o] + nb0v[o], 0.0f) / nn0;
  float g1 = fmaxf(d1*rsqrtf(v1*(1.0f/32.0f)+1e-5f)*ng1v[o] + nb1v[o], 0.0f) / nn1;
  f0o[(size_t)n*32+o] = a0*g0;
  f1o[(size_t)n*96+o*3+0] = ax*g1;
  f1o[(size_t)n*96+o*3+1] = ay*g1;
  f1o[(size_t)n*96+o*3+2] = az*g1;
}

// ---------------- final conv: transposed MFMA, fused loop -> scatter ----------------
__global__ __launch_bounds__(512) void k_fconv_mfma(
    const unsigned short* __restrict__ hbf, const unsigned short* __restrict__ w2s,
    const float* __restrict__ f0, const float* __restrict__ f1,
    const float* __restrict__ rhat, const float* __restrict__ scale,
    const int* __restrict__ src, const int* __restrict__ dst, float* __restrict__ out)
{
  __shared__ float macc[EB][17];
  __shared__ float scs[EB];
  int tid = threadIdx.x;
  int e0 = blockIdx.x * EB;

  for (int idx = tid; idx < EB; idx += 512) scs[idx] = scale[e0+idx];

  int lane = tid & 63, wv = tid >> 6;
  int cl = lane & 15;
  int rb = ((lane >> 4) & 3) * 4;
  int ko = (lane >> 4) * 8;
  int et = wv & 3, gp = wv >> 2;
  int e  = et*16 + cl;

  const unsigned short* hb = hbf + (size_t)e0*64;
  s16x8 bh0 = *reinterpret_cast<const s16x8*>(hb + (size_t)e*64 + ko);
  s16x8 bh1 = *reinterpret_cast<const s16x8*>(hb + (size_t)e*64 + 32 + ko);
  const s16x8* w2v = reinterpret_cast<const s16x8*>(w2s);

  int sn = src[e0+e];
  float rx = rhat[(e0+e)*3+0], ry = rhat[(e0+e)*3+1], rz = rhat[(e0+e)*3+2];
  float F0[8], T1[8];
  #pragma unroll
  for (int r = 0; r < 4; ++r) {
    int cA = rb + r, cB = 16 + rb + r;
    F0[r]   = f0[(size_t)sn*32 + cA];
    F0[4+r] = f0[(size_t)sn*32 + cB];
    float ax0 = f1[(size_t)sn*96 + cA*3 + 0];
    float ax1 = f1[(size_t)sn*96 + cA*3 + 1];
    float ax2 = f1[(size_t)sn*96 + cA*3 + 2];
    float bx0 = f1[(size_t)sn*96 + cB*3 + 0];
    float bx1 = f1[(size_t)sn*96 + cB*3 + 1];
    float bx2 = f1[(size_t)sn*96 + cB*3 + 2];
    T1[r]   = rx*ax0 + ry*ax1 + rz*ax2;
    T1[4+r] = rx*bx0 + ry*bx1 + rz*bx2;
  }

  #pragma unroll 1
  for (int i = 0; i < 8; ++i) {
    int g = 2*i + gp;
    float am;
    {
      f32x4 D0, D1;
      mfma_pair(w2v, g, lane, bh0, bh1, D0, D1);          // Rf00
      float p = 0.f;
      #pragma unroll
      for (int r = 0; r < 4; ++r) { p = fmaf(D0[r], F0[r], p); p = fmaf(D1[r], F0[4+r], p); }
      am = p;
    }
    {
      f32x4 D0, D1;
      mfma_pair(w2v, 16 + g, lane, bh0, bh1, D0, D1);     // Rf10
      float p = 0.f;
      #pragma unroll
      for (int r = 0; r < 4; ++r) { p = fmaf(D0[r], T1[r], p); p = fmaf(D1[r], T1[4+r], p); }
      am += p;
    }
    am += __shfl_xor(am, 16); am += __shfl_xor(am, 32);
    if (lane < 16) macc[e][g] = am;
  }
  __syncthreads();
  for (int idx = tid; idx < EB*16; idx += 512) {
    int e2 = idx >> 4, o = idx & 15;
    atomicAdd(&out[(size_t)dst[e0+e2]*16 + o], macc[e2][o]*scs[e2]);
  }
}

extern "C" void kernel_launch(void* const* d_in, const int* in_sizes, int n_in,
                              void* d_out, int out_size, void* d_ws, size_t ws_size,
                              hipStream_t stream) {
  (void)in_sizes; (void)n_in; (void)ws_size;
  const float* nf0  = (const float*)d_in[0];
  const float* nf1  = (const float*)d_in[1];
  const float* ef0  = (const float*)d_in[2];
  const float* rel  = (const float*)d_in[3];
  const float* scale= (const float*)d_in[4];
  const int*   src  = (const int*)d_in[5];
  const int*   dst  = (const int*)d_in[6];
  const float* rW1  = (const float*)d_in[7];
  const float* rb1  = (const float*)d_in[8];
  const float* rg   = (const float*)d_in[9];
  const float* rbe  = (const float*)d_in[10];
  const float* rW2  = (const float*)d_in[11];
  const float* Wq0  = (const float*)d_in[12];
  const float* Wq1  = (const float*)d_in[13];
  const float* Wp0  = (const float*)d_in[14];
  const float* Wp1  = (const float*)d_in[15];
  const float* ng0  = (const float*)d_in[16];
  const float* nb0  = (const float*)d_in[17];
  const float* ng1  = (const float*)d_in[18];
  const float* nb1  = (const float*)d_in[19];
  const float* fW1  = (const float*)d_in[20];
  const float* fb1  = (const float*)d_in[21];
  const float* fg   = (const float*)d_in[22];
  const float* fbe  = (const float*)d_in[23];
  const float* fW2  = (const float*)d_in[24];

  float* ws = (float*)d_ws;
  size_t off = 0;
  float* es    = ws + off; off += (size_t)NE*5;
  float* rhat  = ws + off; off += (size_t)NE*3;
  float* m     = ws + off; off += (size_t)NE*64;
  float* q     = ws + off; off += (size_t)NN*32;
  float* o0    = ws + off; off += (size_t)NN*8;
  float* o1    = ws + off; off += (size_t)NN*24;
  float* f0a   = ws + off; off += (size_t)NN*32;
  float* f1a   = ws + off; off += (size_t)NN*96;
  float* f0b   = ws + off; off += (size_t)NN*32;
  float* f1b   = ws + off; off += (size_t)NN*96;
  int* cnt     = (int*)(ws + off); off += NN;
  int* offs    = (int*)(ws + off); off += NN + 1;
  int* cursor  = (int*)(ws + off); off += NN;
  int* eidx    = (int*)(ws + off); off += NE;
  unsigned short* usbase = (unsigned short*)(ws + off);
  unsigned short* hbf  = usbase;                               // NE*64
  unsigned short* w2s0 = hbf  + (size_t)NE*64;                 // 96*4*64*8 = 196608
  unsigned short* w2s1 = w2s0 + 196608;
  unsigned short* w2sf = w2s1 + 196608;                        // 32*4*64*8 = 65536

  // CSR build over dst
  hipMemsetAsync(cnt, 0, NN*sizeof(int), stream);
  k_count<<<NE/256, 256, 0, stream>>>(dst, cnt);
  k_scan<<<1, 1024, 0, stream>>>(cnt, offs, cursor);
  k_fill<<<NE/256, 256, 0, stream>>>(dst, cursor, eidx);

  // weight pre-swizzle (bf16 A-fragment order)
  k_w2cvt<<<96, 256, 0, stream>>>(rW2,            w2s0, 3072);
  k_w2cvt<<<96, 256, 0, stream>>>(rW2 + 64*3072,  w2s1, 3072);
  k_w2cvt<<<32, 256, 0, stream>>>(fW2,            w2sf, 1024);

  k_prep<<<NE/256, 256, 0, stream>>>(rel, ef0, es, rhat);

  const float* f0c = nf0; const float* f1c = nf1;
  float* f0n = f0a; float* f1n = f1a;
  for (int l = 0; l < 2; ++l) {
    k_radial<<<NE*64/256, 256, 0, stream>>>(es, rW1 + l*320, rb1 + l*64, rg + l*64, rbe + l*64, hbf);
    k_conv_mfma<<<NE/EB, 512, 0, stream>>>(hbf, (l == 0) ? w2s0 : w2s1, f0c, f1c, rhat, scale, src, m);
    k_query<<<NN/256, 256, 0, stream>>>(f0c, f1c, Wq0 + l*256, Wq1 + l*256, q);
    k_attn<<<NN*8/256, 256, 0, stream>>>(m, q, offs, eidx, o0, o1);
    k_update<<<NN*32/256, 256, 0, stream>>>(o0, o1, f0c, f1c, Wp0 + l*1280, Wp1 + l*1280,
                                            ng0 + l*32, nb0 + l*32, ng1 + l*32, nb1 + l*32,
                                            f0n, f1n);
    f0c = f0n; f1c = f1n; f0n = f0b; f1n = f1b;
  }
  k_radial<<<NE*64/256, 256, 0, stream>>>(es, fW1, fb1, fg, fbe, hbf);
  hipMemsetAsync(d_out, 0, (size_t)out_size*sizeof(float), stream);
  k_fconv_mfma<<<NE/EB, 512, 0, stream>>>(hbf, w2sf, f0c, f1c, rhat, scale, src, dst, (float*)d_out);
}

// Round 13
// 257.132 us; speedup vs baseline: 1.2832x; 1.1365x over previous
//
#include <hip/hip_runtime.h>
#include <math.h>

#define NN 8192
#define NE 32768
#define CC 32
#define EB 64

typedef __attribute__((ext_vector_type(8))) short s16x8;
typedef __attribute__((ext_vector_type(4))) float f32x4;

__device__ __forceinline__ unsigned short f2bf(float f) {
  unsigned u = __float_as_uint(f);
  u += 0x7FFFu + ((u >> 16) & 1u);
  return (unsigned short)(u >> 16);
}

__device__ __forceinline__ void mfma_pair(const s16x8* __restrict__ w2v, int g, int lane,
                                          s16x8 bh0, s16x8 bh1, f32x4& D0, f32x4& D1) {
  const s16x8* ap = w2v + ((size_t)g*4*64 + lane);
  s16x8 a00 = ap[0], a01 = ap[64], a10 = ap[128], a11 = ap[192];
  f32x4 z = {0.f,0.f,0.f,0.f};
  D0 = __builtin_amdgcn_mfma_f32_16x16x32_bf16(a00, bh0, z, 0,0,0);
  D0 = __builtin_amdgcn_mfma_f32_16x16x32_bf16(a01, bh1, D0, 0,0,0);
  D1 = __builtin_amdgcn_mfma_f32_16x16x32_bf16(a10, bh0, z, 0,0,0);
  D1 = __builtin_amdgcn_mfma_f32_16x16x32_bf16(a11, bh1, D1, 0,0,0);
}

// ---------------- edge preprocessing ----------------
__global__ void k_prep(const float* __restrict__ rel, const float* __restrict__ ef,
                       float* __restrict__ es, float* __restrict__ rhat) {
  int e = blockIdx.x * blockDim.x + threadIdx.x;
  if (e >= NE) return;
  float x = rel[e*3+0], y = rel[e*3+1], z = rel[e*3+2];
  float rn = sqrtf(x*x + y*y + z*z);
  float inv = 1.0f / (rn + 1e-12f);
  rhat[e*3+0] = x*inv; rhat[e*3+1] = y*inv; rhat[e*3+2] = z*inv;
  es[e*5+0] = rn;
  es[e*5+1] = ef[e*4+0];
  es[e*5+2] = ef[e*4+1];
  es[e*5+3] = ef[e*4+2];
  es[e*5+4] = ef[e*4+3];
}

// ---------------- CSR build over dst ----------------
__global__ void k_count(const int* __restrict__ dst, int* __restrict__ cnt) {
  int e = blockIdx.x * blockDim.x + threadIdx.x;
  if (e < NE) atomicAdd(&cnt[dst[e]], 1);
}

__global__ __launch_bounds__(1024) void k_scan(const int* __restrict__ cnt,
                                               int* __restrict__ offs, int* __restrict__ cursor) {
  __shared__ int part[1024];
  int t = threadIdx.x;
  int base = t * 8;
  int loc[8];
  int s = 0;
  #pragma unroll
  for (int j = 0; j < 8; ++j) { loc[j] = s; s += cnt[base + j]; }
  part[t] = s;
  __syncthreads();
  for (int off = 1; off < 1024; off <<= 1) {
    int v = (t >= off) ? part[t - off] : 0;
    __syncthreads();
    part[t] += v;
    __syncthreads();
  }
  int pre = (t == 0) ? 0 : part[t - 1];
  #pragma unroll
  for (int j = 0; j < 8; ++j) {
    int o = pre + loc[j];
    offs[base + j] = o;
    cursor[base + j] = o;
  }
  if (t == 1023) offs[NN] = part[1023];
}

__global__ void k_fill(const int* __restrict__ dst, int* __restrict__ cursor,
                       int* __restrict__ eidx) {
  int e = blockIdx.x * blockDim.x + threadIdx.x;
  if (e >= NE) return;
  int pos = atomicAdd(&cursor[dst[e]], 1);
  eidx[pos] = e;
}

// ---------------- W2 -> bf16, A-fragment order — all three weights in one launch ----------------
__global__ void k_w2all(const float* __restrict__ W2a, const float* __restrict__ W2b,
                        const float* __restrict__ W2f,
                        unsigned short* __restrict__ d0, unsigned short* __restrict__ d1,
                        unsigned short* __restrict__ df) {
  int b = blockIdx.x;
  const float* src; unsigned short* dstp; int N; int idx;
  if (b < 96)       { src = W2a; dstp = d0; N = 3072; idx = b*256 + threadIdx.x; }
  else if (b < 192) { src = W2b; dstp = d1; N = 3072; idx = (b-96)*256 + threadIdx.x; }
  else              { src = W2f; dstp = df; N = 1024; idx = (b-192)*256 + threadIdx.x; }
  int total = (N >> 5) * 4 * 64;
  if (idx >= total) return;
  int l = idx & 63;
  int fr = idx >> 6;
  int kh = fr & 1;
  int mt = (fr >> 1) & 1;
  int g  = fr >> 2;
  int kb  = kh*32 + (l >> 4)*8;
  int col = g*32 + mt*16 + (l & 15);
  s16x8 v;
  #pragma unroll
  for (int j = 0; j < 8; ++j) v[j] = (short)f2bf(src[(size_t)(kb + j)*N + col]);
  *reinterpret_cast<s16x8*>(dstp + (size_t)idx*8) = v;
}

// ---------------- fused radial+conv: transposed MFMA, fused phase-loop ----------------
// m layout per edge (64 floats): [0..15]=m0, [16+o*3+a]=m1[o][a]
// 512 thr = 8 waves: et=wv&3 (edge-tile of 16), gp=wv>>2 (group parity). EB=64 edges/block.
__global__ __launch_bounds__(512) void k_conv_mfma(
    const float* __restrict__ es, const float* __restrict__ W1,
    const float* __restrict__ b1, const float* __restrict__ gm,
    const float* __restrict__ be, const unsigned short* __restrict__ w2s,
    const float* __restrict__ f0, const float* __restrict__ f1,
    const float* __restrict__ rhat, const float* __restrict__ scale,
    const int* __restrict__ src, float* __restrict__ m_out)
{
  __shared__ float rhs[EB][4];
  __shared__ float scs[EB];
  __shared__ float macc[EB][81];
  __shared__ unsigned short hs[EB][72];
  int tid = threadIdx.x;
  int e0 = blockIdx.x * EB;
  int lane = tid & 63, wv = tid >> 6;

  for (int idx = tid; idx < EB; idx += 512) {
    rhs[idx][0] = rhat[(e0+idx)*3+0];
    rhs[idx][1] = rhat[(e0+idx)*3+1];
    rhs[idx][2] = rhat[(e0+idx)*3+2];
    scs[idx]    = scale[e0+idx];
  }

  // ---- radial phase: wave wv computes h for edges wv*8..wv*8+7 (lane = mid) ----
  {
    float w1v0 = W1[0*64+lane], w1v1 = W1[1*64+lane], w1v2 = W1[2*64+lane];
    float w1v3 = W1[3*64+lane], w1v4 = W1[4*64+lane];
    float b1v = b1[lane], gv = gm[lane], bev = be[lane];
    #pragma unroll
    for (int j = 0; j < 8; ++j) {
      int ee = wv*8 + j;
      const float* ep = es + (size_t)(e0+ee)*5;
      float v = b1v;
      v = fmaf(ep[0], w1v0, v);
      v = fmaf(ep[1], w1v1, v);
      v = fmaf(ep[2], w1v2, v);
      v = fmaf(ep[3], w1v3, v);
      v = fmaf(ep[4], w1v4, v);
      float s = v;
      #pragma unroll
      for (int off = 32; off; off >>= 1) s += __shfl_xor(s, off);
      float mu = s * (1.0f/64.0f);
      float d = v - mu;
      float s2 = d*d;
      #pragma unroll
      for (int off = 32; off; off >>= 1) s2 += __shfl_xor(s2, off);
      float hv = d * rsqrtf(s2*(1.0f/64.0f) + 1e-5f) * gv + bev;
      hs[ee][lane] = f2bf(fmaxf(hv, 0.0f));
    }
  }
  __syncthreads();

  int cl = lane & 15;
  int rb = ((lane >> 4) & 3) * 4;
  int ko = (lane >> 4) * 8;
  int et = wv & 3, gp = wv >> 2;
  int e  = et*16 + cl;

  s16x8 bh0 = *reinterpret_cast<const s16x8*>(&hs[e][ko]);
  s16x8 bh1 = *reinterpret_cast<const s16x8*>(&hs[e][32 + ko]);
  const s16x8* w2v = reinterpret_cast<const s16x8*>(w2s);

  int sn = src[e0+e];
  float rx = rhs[e][0], ry = rhs[e][1], rz = rhs[e][2];
  float F0[8], T1[8], F1r[24];
  #pragma unroll
  for (int r = 0; r < 4; ++r) {
    int cA = rb + r, cB = 16 + rb + r;
    F0[r]   = f0[(size_t)sn*32 + cA];
    F0[4+r] = f0[(size_t)sn*32 + cB];
    #pragma unroll
    for (int a = 0; a < 3; ++a) {
      F1r[r*3+a]    = f1[(size_t)sn*96 + cA*3 + a];
      F1r[12+r*3+a] = f1[(size_t)sn*96 + cB*3 + a];
    }
  }
  #pragma unroll
  for (int r = 0; r < 4; ++r) {
    T1[r]   = rx*F1r[r*3+0]    + ry*F1r[r*3+1]    + rz*F1r[r*3+2];
    T1[4+r] = rx*F1r[12+r*3+0] + ry*F1r[12+r*3+1] + rz*F1r[12+r*3+2];
  }

  const float inv_s3 = 0.57735026919f;
  const float inv_s2 = 0.70710678118f;
  const float c15    = 1.22474487139f;

  #pragma unroll 1
  for (int i = 0; i < 8; ++i) {
    int g = 2*i + gp;
    float m0v, qv, m1x, m1y, m1z;
    {
      f32x4 D0, D1;
      mfma_pair(w2v, g, lane, bh0, bh1, D0, D1);          // R00
      float p = 0.f;
      #pragma unroll
      for (int r = 0; r < 4; ++r) { p = fmaf(D0[r], F0[r], p); p = fmaf(D1[r], F0[4+r], p); }
      m0v = p;
    }
    {
      f32x4 D0, D1;
      mfma_pair(w2v, 16 + g, lane, bh0, bh1, D0, D1);     // R01 -> q01
      float p = 0.f;
      #pragma unroll
      for (int r = 0; r < 4; ++r) { p = fmaf(D0[r], F0[r], p); p = fmaf(D1[r], F0[4+r], p); }
      qv = p;
    }
    {
      f32x4 D0, D1;
      mfma_pair(w2v, 32 + g, lane, bh0, bh1, D0, D1);     // R10
      float p = 0.f;
      #pragma unroll
      for (int r = 0; r < 4; ++r) { p = fmaf(D0[r], T1[r], p); p = fmaf(D1[r], T1[4+r], p); }
      m0v += p;
    }
    {
      f32x4 D0, D1;
      mfma_pair(w2v, 48 + g, lane, bh0, bh1, D0, D1);     // R11 j3=0 (Q0)
      float v0=0.f, v1=0.f, v2=0.f;
      #pragma unroll
      for (int r = 0; r < 4; ++r) {
        v0 = fmaf(D0[r], F1r[r*3+0], v0); v0 = fmaf(D1[r], F1r[12+r*3+0], v0);
        v1 = fmaf(D0[r], F1r[r*3+1], v1); v1 = fmaf(D1[r], F1r[12+r*3+1], v1);
        v2 = fmaf(D0[r], F1r[r*3+2], v2); v2 = fmaf(D1[r], F1r[12+r*3+2], v2);
      }
      m1x = v0*inv_s3; m1y = v1*inv_s3; m1z = v2*inv_s3;
    }
    {
      f32x4 D0, D1;
      mfma_pair(w2v, 64 + g, lane, bh0, bh1, D0, D1);     // R11 j3=1 (Q1)
      float v0=0.f, v1=0.f, v2=0.f;
      #pragma unroll
      for (int r = 0; r < 4; ++r) {
        v0 = fmaf(D0[r], F1r[r*3+0], v0); v0 = fmaf(D1[r], F1r[12+r*3+0], v0);
        v1 = fmaf(D0[r], F1r[r*3+1], v1); v1 = fmaf(D1[r], F1r[12+r*3+1], v1);
        v2 = fmaf(D0[r], F1r[r*3+2], v2); v2 = fmaf(D1[r], F1r[12+r*3+2], v2);
      }
      m1x += (rz*v1 - ry*v2)*inv_s2;
      m1y += (rx*v2 - rz*v0)*inv_s2;
      m1z += (ry*v0 - rx*v1)*inv_s2;
    }
    {
      f32x4 D0, D1;
      mfma_pair(w2v, 80 + g, lane, bh0, bh1, D0, D1);     // R11 j3=2 (Q2)
      float v0=0.f, v1=0.f, v2=0.f, w=0.f;
      #pragma unroll
      for (int r = 0; r < 4; ++r) {
        v0 = fmaf(D0[r], F1r[r*3+0], v0); v0 = fmaf(D1[r], F1r[12+r*3+0], v0);
        v1 = fmaf(D0[r], F1r[r*3+1], v1); v1 = fmaf(D1[r], F1r[12+r*3+1], v1);
        v2 = fmaf(D0[r], F1r[r*3+2], v2); v2 = fmaf(D1[r], F1r[12+r*3+2], v2);
        w  = fmaf(D0[r], T1[r], w);       w  = fmaf(D1[r], T1[4+r], w);
      }
      m1x += c15*(rx*w - v0*(1.0f/3.0f));
      m1y += c15*(ry*w - v1*(1.0f/3.0f));
      m1z += c15*(rz*w - v2*(1.0f/3.0f));
    }
    m0v += __shfl_xor(m0v, 16); m0v += __shfl_xor(m0v, 32);
    qv  += __shfl_xor(qv,  16); qv  += __shfl_xor(qv,  32);
    m1x += __shfl_xor(m1x, 16); m1x += __shfl_xor(m1x, 32);
    m1y += __shfl_xor(m1y, 16); m1y += __shfl_xor(m1y, 32);
    m1z += __shfl_xor(m1z, 16); m1z += __shfl_xor(m1z, 32);
    if (lane < 16) {
      macc[e][g]          = m0v;
      macc[e][16 + g]     = qv;
      macc[e][32 + g*3+0] = m1x;
      macc[e][32 + g*3+1] = m1y;
      macc[e][32 + g*3+2] = m1z;
    }
  }
  __syncthreads();
  for (int idx = tid; idx < EB*64; idx += 512) {
    int e2 = idx >> 6, t2 = idx & 63;
    float sc = scs[e2];
    float val;
    if (t2 < 16) {
      val = macc[e2][t2] * sc;
    } else {
      int o = (t2-16)/3, a2 = (t2-16)%3;
      val = (macc[e2][32 + (t2-16)] + macc[e2][16+o]*rhs[e2][a2]) * sc;
    }
    m_out[(size_t)(e0+e2)*64 + t2] = val;
  }
}

// ---------------- fused query+attn+update: block = 32 nodes, 3 phases ----------------
__global__ __launch_bounds__(256) void k_qau(
    const float* __restrict__ f0c, const float* __restrict__ f1c,
    const float* __restrict__ Wq0, const float* __restrict__ Wq1,
    const float* __restrict__ m, const int* __restrict__ offs, const int* __restrict__ eidx,
    const float* __restrict__ Wp0, const float* __restrict__ Wp1,
    const float* __restrict__ ng0v, const float* __restrict__ nb0v,
    const float* __restrict__ ng1v, const float* __restrict__ nb1v,
    float* __restrict__ f0o, float* __restrict__ f1o)
{
  __shared__ float qs[32][33];
  __shared__ float os0[32][9];
  __shared__ float os1[32][25];
  int tid = threadIdx.x;
  int n0 = blockIdx.x * 32;

  // Phase A: queries. thread = (nl, k)
  {
    int nl = tid >> 3, k = tid & 7;
    int n = n0 + nl;
    float a0 = 0.f, ax = 0.f, ay = 0.f, az = 0.f;
    for (int c = 0; c < 32; ++c) {
      float w0 = Wq0[c*8+k], w1 = Wq1[c*8+k];
      a0 = fmaf(f0c[(size_t)n*32+c], w0, a0);
      ax = fmaf(f1c[(size_t)n*96+c*3+0], w1, ax);
      ay = fmaf(f1c[(size_t)n*96+c*3+1], w1, ay);
      az = fmaf(f1c[(size_t)n*96+c*3+2], w1, az);
    }
    qs[nl][k]       = a0;
    qs[nl][8+k*3+0] = ax;
    qs[nl][8+k*3+1] = ay;
    qs[nl][8+k*3+2] = az;
  }
  __syncthreads();

  // Phase B: attention (CSR gather + online softmax). thread = (nl, h)
  {
    int nl = tid >> 3, h = tid & 7;
    int n = n0 + nl;
    float q0 = qs[nl][4*h+0], q1 = qs[nl][4*h+1], q2 = qs[nl][4*h+2], q3 = qs[nl][4*h+3];
    int kb = (h < 2) ? 4*h : 8 + 4*h;
    int b0 = offs[n], b1 = offs[n+1];
    float M = -3.4e38f, D = 0.f, A0 = 0.f, Ax = 0.f, Ay = 0.f, Az = 0.f;
    for (int j = b0; j < b1; ++j) {
      int e = eidx[j];
      const float* me = m + (size_t)e*64;
      float4 kv = *reinterpret_cast<const float4*>(me + kb);
      float l = 0.5f * (kv.x*q0 + kv.y*q1 + kv.z*q2 + kv.w*q3);
      float v0 = me[8+h];
      float vx = me[40+3*h], vy = me[41+3*h], vz = me[42+3*h];
      if (l > M) {
        float sc = __expf(M - l);
        D *= sc; A0 *= sc; Ax *= sc; Ay *= sc; Az *= sc;
        M = l;
      }
      float z = __expf(l - M);
      D += z;
      A0 = fmaf(z, v0, A0);
      Ax = fmaf(z, vx, Ax);
      Ay = fmaf(z, vy, Ay);
      Az = fmaf(z, vz, Az);
    }
    float inv = 1.0f / (D + 1e-9f);
    os0[nl][h]     = A0*inv;
    os1[nl][3*h+0] = Ax*inv;
    os1[nl][3*h+1] = Ay*inv;
    os1[nl][3*h+2] = Az*inv;
  }
  __syncthreads();

  // Phase C: projection + NormSE3. 4 passes, thread = (nl = p*8 + tid>>5, o = tid&31)
  #pragma unroll 1
  for (int p = 0; p < 4; ++p) {
    int nl = p*8 + (tid >> 5), o = tid & 31;
    int n = n0 + nl;
    float a0 = 0.f, ax = 0.f, ay = 0.f, az = 0.f;
    #pragma unroll
    for (int c = 0; c < 8; ++c) {
      float w0 = Wp0[c*32+o], w1 = Wp1[c*32+o];
      a0 = fmaf(os0[nl][c], w0, a0);
      ax = fmaf(os1[nl][c*3+0], w1, ax);
      ay = fmaf(os1[nl][c*3+1], w1, ay);
      az = fmaf(os1[nl][c*3+2], w1, az);
    }
    for (int c = 0; c < 32; ++c) {
      float w0 = Wp0[(8+c)*32+o], w1 = Wp1[(8+c)*32+o];
      a0 = fmaf(f0c[(size_t)n*32+c], w0, a0);
      ax = fmaf(f1c[(size_t)n*96+c*3+0], w1, ax);
      ay = fmaf(f1c[(size_t)n*96+c*3+1], w1, ay);
      az = fmaf(f1c[(size_t)n*96+c*3+2], w1, az);
    }
    float nn0 = sqrtf(a0*a0 + 1e-12f);
    float nn1 = sqrtf(ax*ax + ay*ay + az*az + 1e-12f);
    float s0 = nn0, s1 = nn1;
    #pragma unroll
    for (int off = 16; off; off >>= 1) { s0 += __shfl_xor(s0, off, 32); s1 += __shfl_xor(s1, off, 32); }
    float mu0 = s0*(1.0f/32.0f), mu1 = s1*(1.0f/32.0f);
    float d0 = nn0 - mu0, d1 = nn1 - mu1;
    float v0 = d0*d0, v1 = d1*d1;
    #pragma unroll
    for (int off = 16; off; off >>= 1) { v0 += __shfl_xor(v0, off, 32); v1 += __shfl_xor(v1, off, 32); }
    float g0 = fmaxf(d0*rsqrtf(v0*(1.0f/32.0f)+1e-5f)*ng0v[o] + nb0v[o], 0.0f) / nn0;
    float g1 = fmaxf(d1*rsqrtf(v1*(1.0f/32.0f)+1e-5f)*ng1v[o] + nb1v[o], 0.0f) / nn1;
    f0o[(size_t)n*32+o] = a0*g0;
    f1o[(size_t)n*96+o*3+0] = ax*g1;
    f1o[(size_t)n*96+o*3+1] = ay*g1;
    f1o[(size_t)n*96+o*3+2] = az*g1;
  }
}

// ---------------- fused radial+final-conv -> scatter ----------------
__global__ __launch_bounds__(512) void k_fconv_mfma(
    const float* __restrict__ es, const float* __restrict__ W1,
    const float* __restrict__ b1, const float* __restrict__ gm,
    const float* __restrict__ be, const unsigned short* __restrict__ w2s,
    const float* __restrict__ f0, const float* __restrict__ f1,
    const float* __restrict__ rhat, const float* __restrict__ scale,
    const int* __restrict__ src, const int* __restrict__ dst, float* __restrict__ out)
{
  __shared__ float macc[EB][17];
  __shared__ float scs[EB];
  __shared__ unsigned short hs[EB][72];
  int tid = threadIdx.x;
  int e0 = blockIdx.x * EB;
  int lane = tid & 63, wv = tid >> 6;

  for (int idx = tid; idx < EB; idx += 512) scs[idx] = scale[e0+idx];

  {
    float w1v0 = W1[0*64+lane], w1v1 = W1[1*64+lane], w1v2 = W1[2*64+lane];
    float w1v3 = W1[3*64+lane], w1v4 = W1[4*64+lane];
    float b1v = b1[lane], gv = gm[lane], bev = be[lane];
    #pragma unroll
    for (int j = 0; j < 8; ++j) {
      int ee = wv*8 + j;
      const float* ep = es + (size_t)(e0+ee)*5;
      float v = b1v;
      v = fmaf(ep[0], w1v0, v);
      v = fmaf(ep[1], w1v1, v);
      v = fmaf(ep[2], w1v2, v);
      v = fmaf(ep[3], w1v3, v);
      v = fmaf(ep[4], w1v4, v);
      float s = v;
      #pragma unroll
      for (int off = 32; off; off >>= 1) s += __shfl_xor(s, off);
      float mu = s * (1.0f/64.0f);
      float d = v - mu;
      float s2 = d*d;
      #pragma unroll
      for (int off = 32; off; off >>= 1) s2 += __shfl_xor(s2, off);
      float hv = d * rsqrtf(s2*(1.0f/64.0f) + 1e-5f) * gv + bev;
      hs[ee][lane] = f2bf(fmaxf(hv, 0.0f));
    }
  }
  __syncthreads();

  int cl = lane & 15;
  int rb = ((lane >> 4) & 3) * 4;
  int ko = (lane >> 4) * 8;
  int et = wv & 3, gp = wv >> 2;
  int e  = et*16 + cl;

  s16x8 bh0 = *reinterpret_cast<const s16x8*>(&hs[e][ko]);
  s16x8 bh1 = *reinterpret_cast<const s16x8*>(&hs[e][32 + ko]);
  const s16x8* w2v = reinterpret_cast<const s16x8*>(w2s);

  int sn = src[e0+e];
  float rx = rhat[(e0+e)*3+0], ry = rhat[(e0+e)*3+1], rz = rhat[(e0+e)*3+2];
  float F0[8], T1[8];
  #pragma unroll
  for (int r = 0; r < 4; ++r) {
    int cA = rb + r, cB = 16 + rb + r;
    F0[r]   = f0[(size_t)sn*32 + cA];
    F0[4+r] = f0[(size_t)sn*32 + cB];
    float ax0 = f1[(size_t)sn*96 + cA*3 + 0];
    float ax1 = f1[(size_t)sn*96 + cA*3 + 1];
    float ax2 = f1[(size_t)sn*96 + cA*3 + 2];
    float bx0 = f1[(size_t)sn*96 + cB*3 + 0];
    float bx1 = f1[(size_t)sn*96 + cB*3 + 1];
    float bx2 = f1[(size_t)sn*96 + cB*3 + 2];
    T1[r]   = rx*ax0 + ry*ax1 + rz*ax2;
    T1[4+r] = rx*bx0 + ry*bx1 + rz*bx2;
  }

  #pragma unroll 1
  for (int i = 0; i < 8; ++i) {
    int g = 2*i + gp;
    float am;
    {
      f32x4 D0, D1;
      mfma_pair(w2v, g, lane, bh0, bh1, D0, D1);          // Rf00
      float p = 0.f;
      #pragma unroll
      for (int r = 0; r < 4; ++r) { p = fmaf(D0[r], F0[r], p); p = fmaf(D1[r], F0[4+r], p); }
      am = p;
    }
    {
      f32x4 D0, D1;
      mfma_pair(w2v, 16 + g, lane, bh0, bh1, D0, D1);     // Rf10
      float p = 0.f;
      #pragma unroll
      for (int r = 0; r < 4; ++r) { p = fmaf(D0[r], T1[r], p); p = fmaf(D1[r], T1[4+r], p); }
      am += p;
    }
    am += __shfl_xor(am, 16); am += __shfl_xor(am, 32);
    if (lane < 16) macc[e][g] = am;
  }
  __syncthreads();
  for (int idx = tid; idx < EB*16; idx += 512) {
    int e2 = idx >> 4, o = idx & 15;
    atomicAdd(&out[(size_t)dst[e0+e2]*16 + o], macc[e2][o]*scs[e2]);
  }
}

extern "C" void kernel_launch(void* const* d_in, const int* in_sizes, int n_in,
                              void* d_out, int out_size, void* d_ws, size_t ws_size,
                              hipStream_t stream) {
  (void)in_sizes; (void)n_in; (void)ws_size;
  const float* nf0  = (const float*)d_in[0];
  const float* nf1  = (const float*)d_in[1];
  const float* ef0  = (const float*)d_in[2];
  const float* rel  = (const float*)d_in[3];
  const float* scale= (const float*)d_in[4];
  const int*   src  = (const int*)d_in[5];
  const int*   dst  = (const int*)d_in[6];
  const float* rW1  = (const float*)d_in[7];
  const float* rb1  = (const float*)d_in[8];
  const float* rg   = (const float*)d_in[9];
  const float* rbe  = (const float*)d_in[10];
  const float* rW2  = (const float*)d_in[11];
  const float* Wq0  = (const float*)d_in[12];
  const float* Wq1  = (const float*)d_in[13];
  const float* Wp0  = (const float*)d_in[14];
  const float* Wp1  = (const float*)d_in[15];
  const float* ng0  = (const float*)d_in[16];
  const float* nb0  = (const float*)d_in[17];
  const float* ng1  = (const float*)d_in[18];
  const float* nb1  = (const float*)d_in[19];
  const float* fW1  = (const float*)d_in[20];
  const float* fb1  = (const float*)d_in[21];
  const float* fg   = (const float*)d_in[22];
  const float* fbe  = (const float*)d_in[23];
  const float* fW2  = (const float*)d_in[24];

  float* ws = (float*)d_ws;
  size_t off = 0;
  float* es    = ws + off; off += (size_t)NE*5;
  float* rhat  = ws + off; off += (size_t)NE*3;
  float* m     = ws + off; off += (size_t)NE*64;
  float* f0a   = ws + off; off += (size_t)NN*32;
  float* f1a   = ws + off; off += (size_t)NN*96;
  float* f0b   = ws + off; off += (size_t)NN*32;
  float* f1b   = ws + off; off += (size_t)NN*96;
  int* cnt     = (int*)(ws + off); off += NN;
  int* offs    = (int*)(ws + off); off += NN + 1;
  int* cursor  = (int*)(ws + off); off += NN;
  int* eidx    = (int*)(ws + off); off += NE;
  unsigned short* usbase = (unsigned short*)(ws + off);
  unsigned short* w2s0 = usbase;                               // 96*4*64*8 = 196608
  unsigned short* w2s1 = w2s0 + 196608;
  unsigned short* w2sf = w2s1 + 196608;                        // 32*4*64*8 = 65536

  // CSR build over dst
  hipMemsetAsync(cnt, 0, NN*sizeof(int), stream);
  k_count<<<NE/256, 256, 0, stream>>>(dst, cnt);
  k_scan<<<1, 1024, 0, stream>>>(cnt, offs, cursor);
  k_fill<<<NE/256, 256, 0, stream>>>(dst, cursor, eidx);

  // weight pre-swizzle (bf16 A-fragment order), single launch
  k_w2all<<<224, 256, 0, stream>>>(rW2, rW2 + 64*3072, fW2, w2s0, w2s1, w2sf);

  k_prep<<<NE/256, 256, 0, stream>>>(rel, ef0, es, rhat);

  const float* f0c = nf0; const float* f1c = nf1;
  float* f0n = f0a; float* f1n = f1a;
  for (int l = 0; l < 2; ++l) {
    k_conv_mfma<<<NE/EB, 512, 0, stream>>>(es, rW1 + l*320, rb1 + l*64, rg + l*64, rbe + l*64,
                                           (l == 0) ? w2s0 : w2s1, f0c, f1c, rhat, scale, src, m);
    k_qau<<<NN/32, 256, 0, stream>>>(f0c, f1c, Wq0 + l*256, Wq1 + l*256, m, offs, eidx,
                                     Wp0 + l*1280, Wp1 + l*1280,
                                     ng0 + l*32, nb0 + l*32, ng1 + l*32, nb1 + l*32,
                                     f0n, f1n);
    f0c = f0n; f1c = f1n; f0n = f0b; f1n = f1b;
  }
  hipMemsetAsync(d_out, 0, (size_t)out_size*sizeof(float), stream);
  k_fconv_mfma<<<NE/EB, 512, 0, stream>>>(es, fW1, fb1, fg, fbe, w2sf,
                                          f0c, f1c, rhat, scale, src, dst, (float*)d_out);
}